// Round 10
// baseline (273.851 us; speedup 1.0000x reference)
//
#include <hip/hip_runtime.h>
#include <hip/hip_bf16.h>

typedef unsigned short u16;
typedef unsigned int u32;
typedef __attribute__((ext_vector_type(8))) short bf16x8;
typedef __attribute__((ext_vector_type(4))) float f32x4;

#define AS1 __attribute__((address_space(1)))
#define AS3 __attribute__((address_space(3)))

#define M_DIM 8192
#define N_DIM 4096
#define K_DIM 4096
#define NKT   (K_DIM / 64)
#define NITER (NKT / 2)

static __device__ __forceinline__ void gload16(const u16* g, u16* l) {
    __builtin_amdgcn_global_load_lds((const AS1 void*)g, (AS3 void*)l, 16, 0, 0);
}

static __device__ __forceinline__ u16 f2bf_rne(float f) {
    u32 u = __float_as_uint(f);
    u32 r = (u + 0x7fffu + ((u >> 16) & 1u)) >> 16;
    return (u16)r;
}

// ---------------- Kernel 1: convert input fp32 -> bf16 ----------------
__global__ void cvt_a_kernel(const float* __restrict__ In, u16* __restrict__ Ab) {
    size_t i = ((size_t)blockIdx.x * 256 + threadIdx.x) * 8;
    float4 x0 = *(const float4*)(In + i);
    float4 x1 = *(const float4*)(In + i + 4);
    u16 o[8];
    o[0] = f2bf_rne(x0.x); o[1] = f2bf_rne(x0.y); o[2] = f2bf_rne(x0.z); o[3] = f2bf_rne(x0.w);
    o[4] = f2bf_rne(x1.x); o[5] = f2bf_rne(x1.y); o[6] = f2bf_rne(x1.z); o[7] = f2bf_rne(x1.w);
    *(ulong2*)(Ab + i) = *(const ulong2*)o;
}

// ---------------- Kernel 2: dequantize W -> bf16 ----------------
__global__ void dequant_w_kernel(const int* __restrict__ codes,
                                 const float* __restrict__ cbs,
                                 const float* __restrict__ scales,
                                 u16* __restrict__ Wb) {
    int g = blockIdx.x * 256 + threadIdx.x;
    int o = g >> 9;
    int c0 = codes[(size_t)g * 2 + 0];
    int c1 = codes[(size_t)g * 2 + 1];
    float s = scales[o];
    const float4* e0 = (const float4*)(cbs + (size_t)c0 * 8);
    const float4* e1 = (const float4*)(cbs + 2048 + (size_t)c1 * 8);
    float4 a0 = e0[0], a1 = e0[1];
    float4 b0 = e1[0], b1 = e1[1];
    u16 o8[8];
    o8[0] = f2bf_rne(s * (a0.x + b0.x));
    o8[1] = f2bf_rne(s * (a0.y + b0.y));
    o8[2] = f2bf_rne(s * (a0.z + b0.z));
    o8[3] = f2bf_rne(s * (a0.w + b0.w));
    o8[4] = f2bf_rne(s * (a1.x + b1.x));
    o8[5] = f2bf_rne(s * (a1.y + b1.y));
    o8[6] = f2bf_rne(s * (a1.z + b1.z));
    o8[7] = f2bf_rne(s * (a1.w + b1.w));
    *(ulong2*)(Wb + (size_t)g * 8) = *(const ulong2*)o8;
}

// ---------------- Kernel 3: 256x256 8-phase GEMM, 16x16x32 MFMA ----------------
// R9 schedule MINUS all manual lgkmcnt(0)/sched_barrier/sched_group_barrier:
// ds_reads are plain loads -> compiler emits precise per-operand lgkmcnt waits
// and is free to software-pipeline within phases. vmcnt ledger (compiler can't
// derive), end-BARs, minimal fences, and setprio are kept.
// Region-safety proof without manual lgkm0: a phase's MFMA data-depends on its
// ds_reads, so end-BAR passed => reads completed; every STG targets a region
// whose last consuming MFMA sits >=1 end-BAR earlier (checked per phase).

#define FENCE() asm volatile("" ::: "memory")
#define BAR()   __builtin_amdgcn_s_barrier()
#define WAIT_VM4()   asm volatile("s_waitcnt vmcnt(4)" ::: "memory")
#define WAIT_VM6()   asm volatile("s_waitcnt vmcnt(6)" ::: "memory")
#define PRIO1() __builtin_amdgcn_s_setprio(1)
#define PRIO0() __builtin_amdgcn_s_setprio(0)

// A-half mh of buf p -> a[4][2] (4 m-frags x 2 kk-halves), zero-conflict pattern
#define LD_A(p, mh) do { \
    const u16* _rA = &lsA[(p)*16384 + ((mh)*128 + aRB)*64]; \
    a[0][0] = *(const bf16x8*)(_rA + cb0);        a[0][1] = *(const bf16x8*)(_rA + cb1); \
    a[1][0] = *(const bf16x8*)(_rA + 1024 + cb0); a[1][1] = *(const bf16x8*)(_rA + 1024 + cb1); \
    a[2][0] = *(const bf16x8*)(_rA + 2048 + cb0); a[2][1] = *(const bf16x8*)(_rA + 2048 + cb1); \
    a[3][0] = *(const bf16x8*)(_rA + 3072 + cb0); a[3][1] = *(const bf16x8*)(_rA + 3072 + cb1); \
} while (0)

// B-half nh of buf p -> breg[2][2] (2 n-frags x 2 kk-halves)
#define LD_B(p, nh, breg) do { \
    const u16* _rB = &lsB[(p)*16384 + ((nh)*128 + bRB)*64]; \
    breg[0][0] = *(const bf16x8*)(_rB + cb0);        breg[0][1] = *(const bf16x8*)(_rB + cb1); \
    breg[1][0] = *(const bf16x8*)(_rB + 1024 + cb0); breg[1][1] = *(const bf16x8*)(_rB + 1024 + cb1); \
} while (0)

#define MFMA1(am, c, ar, br) acc[am][c] = __builtin_amdgcn_mfma_f32_16x16x32_bf16(ar, br, acc[am][c], 0, 0, 0)
#define MFMA_Q(mh, nh, breg) do { \
    MFMA1((mh)*4+0, (nh)*2+0, a[0][0], breg[0][0]); MFMA1((mh)*4+0, (nh)*2+0, a[0][1], breg[0][1]); \
    MFMA1((mh)*4+0, (nh)*2+1, a[0][0], breg[1][0]); MFMA1((mh)*4+0, (nh)*2+1, a[0][1], breg[1][1]); \
    MFMA1((mh)*4+1, (nh)*2+0, a[1][0], breg[0][0]); MFMA1((mh)*4+1, (nh)*2+0, a[1][1], breg[0][1]); \
    MFMA1((mh)*4+1, (nh)*2+1, a[1][0], breg[1][0]); MFMA1((mh)*4+1, (nh)*2+1, a[1][1], breg[1][1]); \
    MFMA1((mh)*4+2, (nh)*2+0, a[2][0], breg[0][0]); MFMA1((mh)*4+2, (nh)*2+0, a[2][1], breg[0][1]); \
    MFMA1((mh)*4+2, (nh)*2+1, a[2][0], breg[1][0]); MFMA1((mh)*4+2, (nh)*2+1, a[2][1], breg[1][1]); \
    MFMA1((mh)*4+3, (nh)*2+0, a[3][0], breg[0][0]); MFMA1((mh)*4+3, (nh)*2+0, a[3][1], breg[0][1]); \
    MFMA1((mh)*4+3, (nh)*2+1, a[3][0], breg[1][0]); MFMA1((mh)*4+3, (nh)*2+1, a[3][1], breg[1][1]); \
} while (0)

#define STG_A(p, j, kt) gload16(pA[j] + (kt)*64, &lsA[(p)*16384 + (j)*4096 + wOff])
#define STG_B(p, j, kt) gload16(pB[j] + (kt)*64, &lsB[(p)*16384 + (j)*4096 + wOff])

__global__ __launch_bounds__(512, 2)
void gemm8_kernel(const u16* __restrict__ Ab, const u16* __restrict__ Wb,
                  const float* __restrict__ bias, float* __restrict__ Out) {
    __shared__ u16 lsA[2 * 256 * 64];
    __shared__ u16 lsB[2 * 256 * 64];

    const int tid = threadIdx.x;
    const int w = tid >> 6, lane = tid & 63;
    const int wr = w >> 2, wc = w & 3;
    const int l15 = lane & 15, l7 = lane & 7, lq = lane >> 4;

    // T1: XCD-aware bijective swizzle (512 blocks % 8 == 0)
    int raw = blockIdx.x;
    int swz = (raw & 7) * 64 + (raw >> 3);
    const int bm = swz >> 4, bn = swz & 15;
    const int m0 = bm * 256, n0 = bn * 256;

    // read-side bases (verified zero-conflict pattern)
    const int aRB = wr * 64 + l15;
    const int bRB = wc * 32 + l15;
    const int cb0 = ((0 + lq) ^ l7) * 8;
    const int cb1 = ((4 + lq) ^ l7) * 8;

    // staging per-thread values
    const int relRow = tid >> 3;
    const int cbl = (tid & 7) ^ (relRow & 7);
    const int gBaseA[4] = {0, 128, 64, 192};
    const u16* pA[4];
    const u16* pB[4];
#pragma unroll
    for (int j = 0; j < 4; ++j) {
        pA[j] = Ab + (size_t)(m0 + gBaseA[j] + relRow) * K_DIM + cbl * 8;
        int rl = j * 64 + relRow;
        int n = ((rl >> 5) & 3) * 64 + (rl >> 7) * 32 + (rl & 31);
        pB[j] = Wb + (size_t)(n0 + n) * K_DIM + cbl * 8;
    }
    const int wOff = w * 512;

    float bv[4];
#pragma unroll
    for (int c = 0; c < 4; ++c) bv[c] = bias[n0 + wc * 64 + (c >> 1) * 32 + (c & 1) * 16 + l15];

    f32x4 acc[8][4];
#pragma unroll
    for (int am = 0; am < 8; ++am)
#pragma unroll
        for (int c = 0; c < 4; ++c) acc[am][c] = (f32x4){0.f, 0.f, 0.f, 0.f};
    bf16x8 a[4][2], b0a[2][2], b1a[2][2];

    // ---- prologue: buf0 <- kt0 (4 half-tiles), buf1 <- kt1 (A0,B0,A1) ----
    STG_A(0, 0, 0); STG_A(0, 1, 0); STG_A(0, 2, 0); STG_A(0, 3, 0);
    STG_B(0, 0, 0); STG_B(0, 1, 0); STG_B(0, 2, 0); STG_B(0, 3, 0);
    STG_A(1, 0, 1); STG_A(1, 1, 1);
    STG_B(1, 0, 1); STG_B(1, 1, 1);
    STG_A(1, 2, 1); STG_A(1, 3, 1);
    WAIT_VM6();                 // bias(4)+buf0(8) drained; 6 buf1 ops in flight
    FENCE(); BAR(); FENCE();
    LD_A(0, 0); LD_B(0, 0, b0a);   // reads for P1 (buf0 published)
    FENCE();

#pragma unroll 1
    for (int i = 0; i < NITER; ++i) {
        const int t1  = 2 * i + 1;
        const int kt2 = (2 * i + 2) & (NKT - 1);   // wraps harmlessly on last iter
        const int kt3 = (2 * i + 3) & (NKT - 1);

        // P1: Q(0,0) buf0 | post: b1 <- buf0.nh1 | STG buf1.B(nh1) <- t1
        STG_B(1, 2, t1); STG_B(1, 3, t1);
        PRIO1(); MFMA_Q(0, 0, b0a); PRIO0();
        LD_B(0, 1, b1a);
        FENCE(); BAR();

        // P2: Q(0,1) buf0 | post: a <- buf0.mh1 | STG buf0.A(mh0) <- kt2
        STG_A(0, 0, kt2); STG_A(0, 1, kt2);
        PRIO1(); MFMA_Q(0, 1, b1a); PRIO0();
        LD_A(0, 1);
        FENCE(); BAR();

        // P3: Q(1,0) buf0 | STG buf0.B(nh0) | VM4: buf1(t1) landed | publish
        //     post-BAR: b0 <- buf1.nh0 (drains under P4's MFMA)
        STG_B(0, 0, kt2); STG_B(0, 1, kt2);
        PRIO1(); MFMA_Q(1, 0, b0a); PRIO0();
        WAIT_VM4();
        FENCE(); BAR(); FENCE();
        LD_B(1, 0, b0a);

        // P4: Q(1,1) buf0 | STG buf0.A(mh1) | post-BAR: a <- buf1.mh0
        STG_A(0, 2, kt2); STG_A(0, 3, kt2);
        PRIO1(); MFMA_Q(1, 1, b1a); PRIO0();
        FENCE(); BAR(); FENCE();
        LD_A(1, 0);

        // P5: Q(0,0) buf1 | post: b1 <- buf1.nh1 | STG buf0.B(nh1) <- kt2
        STG_B(0, 2, kt2); STG_B(0, 3, kt2);
        PRIO1(); MFMA_Q(0, 0, b0a); PRIO0();
        LD_B(1, 1, b1a);
        FENCE(); BAR();

        // P6: Q(0,1) buf1 | post: a <- buf1.mh1 | STG buf1.A(mh0) <- kt3
        STG_A(1, 0, kt3); STG_A(1, 1, kt3);
        PRIO1(); MFMA_Q(0, 1, b1a); PRIO0();
        LD_A(1, 1);
        FENCE(); BAR();

        // P7: Q(1,0) buf1 | STG buf1.B(nh0) | VM4: buf0(kt2) landed | publish
        //     post-BAR: b0 <- buf0.nh0
        STG_B(1, 0, kt3); STG_B(1, 1, kt3);
        PRIO1(); MFMA_Q(1, 0, b0a); PRIO0();
        WAIT_VM4();
        FENCE(); BAR(); FENCE();
        LD_B(0, 0, b0a);

        // P8: Q(1,1) buf1 | STG buf1.A(mh1) | post-BAR: a <- buf0.mh0
        STG_A(1, 2, kt3); STG_A(1, 3, kt3);
        PRIO1(); MFMA_Q(1, 1, b1a); PRIO0();
        FENCE(); BAR(); FENCE();
        LD_A(0, 0);
    }

    // ---- epilogue: C/D layout col=lane&15, row=(lane>>4)*4+j ----
#pragma unroll
    for (int am = 0; am < 8; ++am) {
        const int gm = m0 + wr * 128 + (am >> 2) * 64 + (am & 3) * 16 + lq * 4;
#pragma unroll
        for (int c = 0; c < 4; ++c) {
            const int gn = n0 + wc * 64 + (c >> 1) * 32 + (c & 1) * 16 + l15;
            float* op = Out + (size_t)gm * N_DIM + gn;
#pragma unroll
            for (int j = 0; j < 4; ++j)
                op[(size_t)j * N_DIM] = acc[am][c][j] + bv[c];
        }
    }
}

// ---------------- Fallback: naive fused fp32 ----------------
__global__ void naive_kernel(const float* __restrict__ In, const int* __restrict__ codes,
                             const float* __restrict__ cbs, const float* __restrict__ scales,
                             const float* __restrict__ bias, float* __restrict__ Out) {
    int m = blockIdx.x >> 4;
    int n = ((blockIdx.x & 15) << 8) + threadIdx.x;
    const float* x = In + (size_t)m * K_DIM;
    const int* cr = codes + (size_t)n * 512 * 2;
    float acc = 0.f;
    for (int ig = 0; ig < 512; ++ig) {
        int c0 = cr[ig * 2], c1 = cr[ig * 2 + 1];
        const float* e0 = cbs + (size_t)c0 * 8;
        const float* e1 = cbs + 2048 + (size_t)c1 * 8;
        const float* xx = x + ig * 8;
#pragma unroll
        for (int j = 0; j < 8; ++j) acc += xx[j] * (e0[j] + e1[j]);
    }
    Out[(size_t)m * N_DIM + n] = acc * scales[n] + bias[n];
}

extern "C" void kernel_launch(void* const* d_in, const int* in_sizes, int n_in,
                              void* d_out, int out_size, void* d_ws, size_t ws_size,
                              hipStream_t stream) {
    const float* In     = (const float*)d_in[0];
    const int*   codes  = (const int*)d_in[1];
    const float* cbs    = (const float*)d_in[2];
    const float* scales = (const float*)d_in[3];
    const float* bias   = (const float*)d_in[4];
    float* Out = (float*)d_out;

    const size_t aBytes = (size_t)M_DIM * K_DIM * 2;
    const size_t wBytes = (size_t)N_DIM * K_DIM * 2;
    if (ws_size >= aBytes + wBytes) {
        u16* Ab = (u16*)d_ws;
        u16* Wb = (u16*)((char*)d_ws + aBytes);
        cvt_a_kernel<<<dim3((M_DIM * K_DIM) / (256 * 8)), dim3(256), 0, stream>>>(In, Ab);
        dequant_w_kernel<<<dim3((N_DIM * 512) / 256), dim3(256), 0, stream>>>(codes, cbs, scales, Wb);
        gemm8_kernel<<<dim3((M_DIM / 256) * (N_DIM / 256)), dim3(512), 0, stream>>>(Ab, Wb, bias, Out);
    } else {
        naive_kernel<<<dim3(M_DIM * (N_DIM / 256)), dim3(256), 0, stream>>>(In, codes, cbs, scales, bias, Out);
    }
}

// Round 11
// 266.558 us; speedup vs baseline: 1.0274x; 1.0274x over previous
//
#include <hip/hip_runtime.h>
#include <hip/hip_bf16.h>

typedef unsigned short u16;
typedef unsigned int u32;
typedef __attribute__((ext_vector_type(8))) short bf16x8;
typedef __attribute__((ext_vector_type(4))) float f32x4;

#define AS1 __attribute__((address_space(1)))
#define AS3 __attribute__((address_space(3)))

#define M_DIM 8192
#define N_DIM 4096
#define K_DIM 4096
#define NKT   (K_DIM / 64)
#define NITER (NKT / 2)

static __device__ __forceinline__ void gload16(const u16* g, u16* l) {
    __builtin_amdgcn_global_load_lds((const AS1 void*)g, (AS3 void*)l, 16, 0, 0);
}

static __device__ __forceinline__ u16 f2bf_rne(float f) {
    u32 u = __float_as_uint(f);
    u32 r = (u + 0x7fffu + ((u >> 16) & 1u)) >> 16;
    return (u16)r;
}

// ---------------- Kernel 1: convert input fp32 -> bf16 ----------------
__global__ void cvt_a_kernel(const float* __restrict__ In, u16* __restrict__ Ab) {
    size_t i = ((size_t)blockIdx.x * 256 + threadIdx.x) * 8;
    float4 x0 = *(const float4*)(In + i);
    float4 x1 = *(const float4*)(In + i + 4);
    u16 o[8];
    o[0] = f2bf_rne(x0.x); o[1] = f2bf_rne(x0.y); o[2] = f2bf_rne(x0.z); o[3] = f2bf_rne(x0.w);
    o[4] = f2bf_rne(x1.x); o[5] = f2bf_rne(x1.y); o[6] = f2bf_rne(x1.z); o[7] = f2bf_rne(x1.w);
    *(ulong2*)(Ab + i) = *(const ulong2*)o;
}

// ---------------- Kernel 2: dequantize W -> bf16 ----------------
__global__ void dequant_w_kernel(const int* __restrict__ codes,
                                 const float* __restrict__ cbs,
                                 const float* __restrict__ scales,
                                 u16* __restrict__ Wb) {
    int g = blockIdx.x * 256 + threadIdx.x;
    int o = g >> 9;
    int c0 = codes[(size_t)g * 2 + 0];
    int c1 = codes[(size_t)g * 2 + 1];
    float s = scales[o];
    const float4* e0 = (const float4*)(cbs + (size_t)c0 * 8);
    const float4* e1 = (const float4*)(cbs + 2048 + (size_t)c1 * 8);
    float4 a0 = e0[0], a1 = e0[1];
    float4 b0 = e1[0], b1 = e1[1];
    u16 o8[8];
    o8[0] = f2bf_rne(s * (a0.x + b0.x));
    o8[1] = f2bf_rne(s * (a0.y + b0.y));
    o8[2] = f2bf_rne(s * (a0.z + b0.z));
    o8[3] = f2bf_rne(s * (a0.w + b0.w));
    o8[4] = f2bf_rne(s * (a1.x + b1.x));
    o8[5] = f2bf_rne(s * (a1.y + b1.y));
    o8[6] = f2bf_rne(s * (a1.z + b1.z));
    o8[7] = f2bf_rne(s * (a1.w + b1.w));
    *(ulong2*)(Wb + (size_t)g * 8) = *(const ulong2*)o8;
}

// ---------------- Kernel 3: 256x256 8-phase GEMM, 16x16x32 MFMA ----------------
// R9 schedule (best measured: lgkm0+SCHEDB per phase, SGB interleave, early
// publish VM4@P3/P7) + P4/P8 now SGB-interleave the fresh B-half read into
// their MFMA burst (regs disjoint; buf published at preceding VM4+BAR).

#define FENCE() asm volatile("" ::: "memory")
#define BAR()   __builtin_amdgcn_s_barrier()
#define WAIT_LGKM0() asm volatile("s_waitcnt lgkmcnt(0)" ::: "memory")
#define WAIT_VM4()   asm volatile("s_waitcnt vmcnt(4)" ::: "memory")
#define WAIT_VM6()   asm volatile("s_waitcnt vmcnt(6)" ::: "memory")
#define SCHEDB() __builtin_amdgcn_sched_barrier(0)
#define PRIO1() __builtin_amdgcn_s_setprio(1)
#define PRIO0() __builtin_amdgcn_s_setprio(0)
#define SGB(m, n) __builtin_amdgcn_sched_group_barrier(m, n, 0)
#define SGB_MIX4() do { \
    SGB(0x8, 4); SGB(0x100, 1); SGB(0x8, 4); SGB(0x100, 1); \
    SGB(0x8, 4); SGB(0x100, 1); SGB(0x8, 4); SGB(0x100, 1); \
} while (0)
#define SGB_MIX8() do { \
    SGB(0x8, 2); SGB(0x100, 1); SGB(0x8, 2); SGB(0x100, 1); \
    SGB(0x8, 2); SGB(0x100, 1); SGB(0x8, 2); SGB(0x100, 1); \
    SGB(0x8, 2); SGB(0x100, 1); SGB(0x8, 2); SGB(0x100, 1); \
    SGB(0x8, 2); SGB(0x100, 1); SGB(0x8, 2); SGB(0x100, 1); \
} while (0)

// A-half mh of buf p -> a[4][2] (4 m-frags x 2 kk-halves), zero-conflict pattern
#define LD_A(p, mh) do { \
    const u16* _rA = &lsA[(p)*16384 + ((mh)*128 + aRB)*64]; \
    a[0][0] = *(const bf16x8*)(_rA + cb0);        a[0][1] = *(const bf16x8*)(_rA + cb1); \
    a[1][0] = *(const bf16x8*)(_rA + 1024 + cb0); a[1][1] = *(const bf16x8*)(_rA + 1024 + cb1); \
    a[2][0] = *(const bf16x8*)(_rA + 2048 + cb0); a[2][1] = *(const bf16x8*)(_rA + 2048 + cb1); \
    a[3][0] = *(const bf16x8*)(_rA + 3072 + cb0); a[3][1] = *(const bf16x8*)(_rA + 3072 + cb1); \
} while (0)

// B-half nh of buf p -> breg[2][2] (2 n-frags x 2 kk-halves)
#define LD_B(p, nh, breg) do { \
    const u16* _rB = &lsB[(p)*16384 + ((nh)*128 + bRB)*64]; \
    breg[0][0] = *(const bf16x8*)(_rB + cb0);        breg[0][1] = *(const bf16x8*)(_rB + cb1); \
    breg[1][0] = *(const bf16x8*)(_rB + 1024 + cb0); breg[1][1] = *(const bf16x8*)(_rB + 1024 + cb1); \
} while (0)

#define MFMA1(am, c, ar, br) acc[am][c] = __builtin_amdgcn_mfma_f32_16x16x32_bf16(ar, br, acc[am][c], 0, 0, 0)
#define MFMA_Q(mh, nh, breg) do { \
    MFMA1((mh)*4+0, (nh)*2+0, a[0][0], breg[0][0]); MFMA1((mh)*4+0, (nh)*2+0, a[0][1], breg[0][1]); \
    MFMA1((mh)*4+0, (nh)*2+1, a[0][0], breg[1][0]); MFMA1((mh)*4+0, (nh)*2+1, a[0][1], breg[1][1]); \
    MFMA1((mh)*4+1, (nh)*2+0, a[1][0], breg[0][0]); MFMA1((mh)*4+1, (nh)*2+0, a[1][1], breg[0][1]); \
    MFMA1((mh)*4+1, (nh)*2+1, a[1][0], breg[1][0]); MFMA1((mh)*4+1, (nh)*2+1, a[1][1], breg[1][1]); \
    MFMA1((mh)*4+2, (nh)*2+0, a[2][0], breg[0][0]); MFMA1((mh)*4+2, (nh)*2+0, a[2][1], breg[0][1]); \
    MFMA1((mh)*4+2, (nh)*2+1, a[2][0], breg[1][0]); MFMA1((mh)*4+2, (nh)*2+1, a[2][1], breg[1][1]); \
    MFMA1((mh)*4+3, (nh)*2+0, a[3][0], breg[0][0]); MFMA1((mh)*4+3, (nh)*2+0, a[3][1], breg[0][1]); \
    MFMA1((mh)*4+3, (nh)*2+1, a[3][0], breg[1][0]); MFMA1((mh)*4+3, (nh)*2+1, a[3][1], breg[1][1]); \
} while (0)

#define STG_A(p, j, kt) gload16(pA[j] + (kt)*64, &lsA[(p)*16384 + (j)*4096 + wOff])
#define STG_B(p, j, kt) gload16(pB[j] + (kt)*64, &lsB[(p)*16384 + (j)*4096 + wOff])

__global__ __launch_bounds__(512, 2)
void gemm8_kernel(const u16* __restrict__ Ab, const u16* __restrict__ Wb,
                  const float* __restrict__ bias, float* __restrict__ Out) {
    __shared__ u16 lsA[2 * 256 * 64];
    __shared__ u16 lsB[2 * 256 * 64];

    const int tid = threadIdx.x;
    const int w = tid >> 6, lane = tid & 63;
    const int wr = w >> 2, wc = w & 3;
    const int l15 = lane & 15, l7 = lane & 7, lq = lane >> 4;

    // T1: XCD-aware bijective swizzle (512 blocks % 8 == 0)
    int raw = blockIdx.x;
    int swz = (raw & 7) * 64 + (raw >> 3);
    const int bm = swz >> 4, bn = swz & 15;
    const int m0 = bm * 256, n0 = bn * 256;

    // read-side bases (verified zero-conflict pattern)
    const int aRB = wr * 64 + l15;
    const int bRB = wc * 32 + l15;
    const int cb0 = ((0 + lq) ^ l7) * 8;
    const int cb1 = ((4 + lq) ^ l7) * 8;

    // staging per-thread values
    const int relRow = tid >> 3;
    const int cbl = (tid & 7) ^ (relRow & 7);
    const int gBaseA[4] = {0, 128, 64, 192};
    const u16* pA[4];
    const u16* pB[4];
#pragma unroll
    for (int j = 0; j < 4; ++j) {
        pA[j] = Ab + (size_t)(m0 + gBaseA[j] + relRow) * K_DIM + cbl * 8;
        int rl = j * 64 + relRow;
        int n = ((rl >> 5) & 3) * 64 + (rl >> 7) * 32 + (rl & 31);
        pB[j] = Wb + (size_t)(n0 + n) * K_DIM + cbl * 8;
    }
    const int wOff = w * 512;

    float bv[4];
#pragma unroll
    for (int c = 0; c < 4; ++c) bv[c] = bias[n0 + wc * 64 + (c >> 1) * 32 + (c & 1) * 16 + l15];

    f32x4 acc[8][4];
#pragma unroll
    for (int am = 0; am < 8; ++am)
#pragma unroll
        for (int c = 0; c < 4; ++c) acc[am][c] = (f32x4){0.f, 0.f, 0.f, 0.f};
    bf16x8 a[4][2], b0a[2][2], b1a[2][2];

    // ---- prologue: buf0 <- kt0 (4 half-tiles), buf1 <- kt1 (A0,B0,A1) ----
    STG_A(0, 0, 0); STG_A(0, 1, 0); STG_A(0, 2, 0); STG_A(0, 3, 0);
    STG_B(0, 0, 0); STG_B(0, 1, 0); STG_B(0, 2, 0); STG_B(0, 3, 0);
    STG_A(1, 0, 1); STG_A(1, 1, 1);
    STG_B(1, 0, 1); STG_B(1, 1, 1);
    STG_A(1, 2, 1); STG_A(1, 3, 1);
    WAIT_VM6();                 // bias+buf0 drained; 6 buf1 ops in flight
    FENCE(); BAR();
    LD_A(0, 0); LD_B(0, 0, b0a);   // reads for P1 (buf0 published)
    FENCE();

#pragma unroll 1
    for (int i = 0; i < NITER; ++i) {
        const int t1  = 2 * i + 1;
        const int kt2 = (2 * i + 2) & (NKT - 1);   // wraps harmlessly on last iter
        const int kt3 = (2 * i + 3) & (NKT - 1);

        // P1: Q(0,0) buf0 ∥ LD b1<-buf0.nh1 (SGB) | STG buf1.B(nh1) <- t1
        STG_B(1, 2, t1); STG_B(1, 3, t1);
        FENCE(); WAIT_LGKM0(); SCHEDB();
        PRIO1(); MFMA_Q(0, 0, b0a); PRIO0();
        LD_B(0, 1, b1a);
        SGB_MIX4();
        FENCE(); BAR();

        // P2: Q(0,1) buf0 ∥ LD a<-buf0.mh1 (SGB) | STG buf0.A(mh0) <- kt2
        STG_A(0, 0, kt2); STG_A(0, 1, kt2);
        FENCE(); WAIT_LGKM0(); SCHEDB();
        PRIO1(); MFMA_Q(0, 1, b1a); PRIO0();
        LD_A(0, 1);
        SGB_MIX8();
        FENCE(); BAR();

        // P3: Q(1,0) buf0 | STG buf0.B(nh0) | VM4: buf1(t1) landed | publish
        STG_B(0, 0, kt2); STG_B(0, 1, kt2);
        FENCE(); WAIT_LGKM0(); SCHEDB();
        PRIO1(); MFMA_Q(1, 0, b0a); PRIO0();
        WAIT_VM4();
        FENCE(); BAR(); FENCE();

        // P4: Q(1,1) buf0 ∥ LD b0 <- buf1.nh0 (SGB; published at P3) | STG buf0.A(mh1)
        //     post-BAR: a <- buf1.mh0
        STG_A(0, 2, kt2); STG_A(0, 3, kt2);
        FENCE();
        PRIO1(); MFMA_Q(1, 1, b1a); PRIO0();
        LD_B(1, 0, b0a);
        SGB_MIX4();
        FENCE(); BAR(); FENCE();
        LD_A(1, 0);

        // P5: Q(0,0) buf1 ∥ LD b1<-buf1.nh1 (SGB) | STG buf0.B(nh1) <- kt2
        STG_B(0, 2, kt2); STG_B(0, 3, kt2);
        FENCE(); WAIT_LGKM0(); SCHEDB();
        PRIO1(); MFMA_Q(0, 0, b0a); PRIO0();
        LD_B(1, 1, b1a);
        SGB_MIX4();
        FENCE(); BAR();

        // P6: Q(0,1) buf1 ∥ LD a<-buf1.mh1 (SGB) | STG buf1.A(mh0) <- kt3
        STG_A(1, 0, kt3); STG_A(1, 1, kt3);
        FENCE(); WAIT_LGKM0(); SCHEDB();
        PRIO1(); MFMA_Q(0, 1, b1a); PRIO0();
        LD_A(1, 1);
        SGB_MIX8();
        FENCE(); BAR();

        // P7: Q(1,0) buf1 | STG buf1.B(nh0) | VM4: buf0(kt2) landed | publish
        STG_B(1, 0, kt3); STG_B(1, 1, kt3);
        FENCE(); WAIT_LGKM0(); SCHEDB();
        PRIO1(); MFMA_Q(1, 0, b0a); PRIO0();
        WAIT_VM4();
        FENCE(); BAR(); FENCE();

        // P8: Q(1,1) buf1 ∥ LD b0 <- buf0.nh0 (SGB) | STG buf1.A(mh1)
        //     post-BAR: a <- buf0.mh0 (next iter P1)
        STG_A(1, 2, kt3); STG_A(1, 3, kt3);
        FENCE();
        PRIO1(); MFMA_Q(1, 1, b1a); PRIO0();
        LD_B(0, 0, b0a);
        SGB_MIX4();
        FENCE(); BAR(); FENCE();
        LD_A(0, 0);
    }

    // ---- epilogue: C/D layout col=lane&15, row=(lane>>4)*4+j ----
#pragma unroll
    for (int am = 0; am < 8; ++am) {
        const int gm = m0 + wr * 128 + (am >> 2) * 64 + (am & 3) * 16 + lq * 4;
#pragma unroll
        for (int c = 0; c < 4; ++c) {
            const int gn = n0 + wc * 64 + (c >> 1) * 32 + (c & 1) * 16 + l15;
            float* op = Out + (size_t)gm * N_DIM + gn;
#pragma unroll
            for (int j = 0; j < 4; ++j)
                op[(size_t)j * N_DIM] = acc[am][c][j] + bv[c];
        }
    }
}

// ---------------- Fallback: naive fused fp32 ----------------
__global__ void naive_kernel(const float* __restrict__ In, const int* __restrict__ codes,
                             const float* __restrict__ cbs, const float* __restrict__ scales,
                             const float* __restrict__ bias, float* __restrict__ Out) {
    int m = blockIdx.x >> 4;
    int n = ((blockIdx.x & 15) << 8) + threadIdx.x;
    const float* x = In + (size_t)m * K_DIM;
    const int* cr = codes + (size_t)n * 512 * 2;
    float acc = 0.f;
    for (int ig = 0; ig < 512; ++ig) {
        int c0 = cr[ig * 2], c1 = cr[ig * 2 + 1];
        const float* e0 = cbs + (size_t)c0 * 8;
        const float* e1 = cbs + 2048 + (size_t)c1 * 8;
        const float* xx = x + ig * 8;
#pragma unroll
        for (int j = 0; j < 8; ++j) acc += xx[j] * (e0[j] + e1[j]);
    }
    Out[(size_t)m * N_DIM + n] = acc * scales[n] + bias[n];
}

extern "C" void kernel_launch(void* const* d_in, const int* in_sizes, int n_in,
                              void* d_out, int out_size, void* d_ws, size_t ws_size,
                              hipStream_t stream) {
    const float* In     = (const float*)d_in[0];
    const int*   codes  = (const int*)d_in[1];
    const float* cbs    = (const float*)d_in[2];
    const float* scales = (const float*)d_in[3];
    const float* bias   = (const float*)d_in[4];
    float* Out = (float*)d_out;

    const size_t aBytes = (size_t)M_DIM * K_DIM * 2;
    const size_t wBytes = (size_t)N_DIM * K_DIM * 2;
    if (ws_size >= aBytes + wBytes) {
        u16* Ab = (u16*)d_ws;
        u16* Wb = (u16*)((char*)d_ws + aBytes);
        cvt_a_kernel<<<dim3((M_DIM * K_DIM) / (256 * 8)), dim3(256), 0, stream>>>(In, Ab);
        dequant_w_kernel<<<dim3((N_DIM * 512) / 256), dim3(256), 0, stream>>>(codes, cbs, scales, Wb);
        gemm8_kernel<<<dim3((M_DIM / 256) * (N_DIM / 256)), dim3(512), 0, stream>>>(Ab, Wb, bias, Out);
    } else {
        naive_kernel<<<dim3(M_DIM * (N_DIM / 256)), dim3(256), 0, stream>>>(In, codes, cbs, scales, bias, Out);
    }
}

// Round 13
// 266.329 us; speedup vs baseline: 1.0282x; 1.0009x over previous
//
#include <hip/hip_runtime.h>
#include <hip/hip_bf16.h>

typedef unsigned short u16;
typedef unsigned int u32;
typedef __attribute__((ext_vector_type(8))) short bf16x8;
typedef __attribute__((ext_vector_type(4))) float f32x4;

#define AS1 __attribute__((address_space(1)))
#define AS3 __attribute__((address_space(3)))

#define M_DIM 8192
#define N_DIM 4096
#define K_DIM 4096
#define NKT   (K_DIM / 64)
#define NITER (NKT / 2)

static __device__ __forceinline__ void gload16(const u16* g, u16* l) {
    __builtin_amdgcn_global_load_lds((const AS1 void*)g, (AS3 void*)l, 16, 0, 0);
}

static __device__ __forceinline__ u16 f2bf_rne(float f) {
    u32 u = __float_as_uint(f);
    u32 r = (u + 0x7fffu + ((u >> 16) & 1u)) >> 16;
    return (u16)r;
}

// ---------------- Kernel 1: convert input fp32 -> bf16 ----------------
__global__ void cvt_a_kernel(const float* __restrict__ In, u16* __restrict__ Ab) {
    size_t i = ((size_t)blockIdx.x * 256 + threadIdx.x) * 8;
    float4 x0 = *(const float4*)(In + i);
    float4 x1 = *(const float4*)(In + i + 4);
    u16 o[8];
    o[0] = f2bf_rne(x0.x); o[1] = f2bf_rne(x0.y); o[2] = f2bf_rne(x0.z); o[3] = f2bf_rne(x0.w);
    o[4] = f2bf_rne(x1.x); o[5] = f2bf_rne(x1.y); o[6] = f2bf_rne(x1.z); o[7] = f2bf_rne(x1.w);
    *(ulong2*)(Ab + i) = *(const ulong2*)o;
}

// ---------------- Kernel 2: dequantize W -> bf16 ----------------
__global__ void dequant_w_kernel(const int* __restrict__ codes,
                                 const float* __restrict__ cbs,
                                 const float* __restrict__ scales,
                                 u16* __restrict__ Wb) {
    int g = blockIdx.x * 256 + threadIdx.x;
    int o = g >> 9;
    int c0 = codes[(size_t)g * 2 + 0];
    int c1 = codes[(size_t)g * 2 + 1];
    float s = scales[o];
    const float4* e0 = (const float4*)(cbs + (size_t)c0 * 8);
    const float4* e1 = (const float4*)(cbs + 2048 + (size_t)c1 * 8);
    float4 a0 = e0[0], a1 = e0[1];
    float4 b0 = e1[0], b1 = e1[1];
    u16 o8[8];
    o8[0] = f2bf_rne(s * (a0.x + b0.x));
    o8[1] = f2bf_rne(s * (a0.y + b0.y));
    o8[2] = f2bf_rne(s * (a0.z + b0.z));
    o8[3] = f2bf_rne(s * (a0.w + b0.w));
    o8[4] = f2bf_rne(s * (a1.x + b1.x));
    o8[5] = f2bf_rne(s * (a1.y + b1.y));
    o8[6] = f2bf_rne(s * (a1.z + b1.z));
    o8[7] = f2bf_rne(s * (a1.w + b1.w));
    *(ulong2*)(Wb + (size_t)g * 8) = *(const ulong2*)o8;
}

// ---------------- Kernel 3: 256x256 8-phase GEMM, 16x16x32 MFMA ----------------
// R11 (best verified): lgkm0+SCHEDB per phase, SGB MFMA/DS interleave, early
// publish VM4@P3/P7, P4/P8 SGB-interleave fresh B-half read, 8 barriers/iter.
// R12's 6-barrier variant RACES (P4's interleaved LD_B drains at P5-lgkm0,
// after P4-end BAR; removing P5-end BAR lets a fast wave's P6 STG overwrite
// buf1.nh0 under a slow wave's pending reads). Do not remove P1/P5 barriers
// without re-deriving the full staging ledger.

#define FENCE() asm volatile("" ::: "memory")
#define BAR()   __builtin_amdgcn_s_barrier()
#define WAIT_LGKM0() asm volatile("s_waitcnt lgkmcnt(0)" ::: "memory")
#define WAIT_VM4()   asm volatile("s_waitcnt vmcnt(4)" ::: "memory")
#define WAIT_VM6()   asm volatile("s_waitcnt vmcnt(6)" ::: "memory")
#define SCHEDB() __builtin_amdgcn_sched_barrier(0)
#define PRIO1() __builtin_amdgcn_s_setprio(1)
#define PRIO0() __builtin_amdgcn_s_setprio(0)
#define SGB(m, n) __builtin_amdgcn_sched_group_barrier(m, n, 0)
#define SGB_MIX4() do { \
    SGB(0x8, 4); SGB(0x100, 1); SGB(0x8, 4); SGB(0x100, 1); \
    SGB(0x8, 4); SGB(0x100, 1); SGB(0x8, 4); SGB(0x100, 1); \
} while (0)
#define SGB_MIX8() do { \
    SGB(0x8, 2); SGB(0x100, 1); SGB(0x8, 2); SGB(0x100, 1); \
    SGB(0x8, 2); SGB(0x100, 1); SGB(0x8, 2); SGB(0x100, 1); \
    SGB(0x8, 2); SGB(0x100, 1); SGB(0x8, 2); SGB(0x100, 1); \
    SGB(0x8, 2); SGB(0x100, 1); SGB(0x8, 2); SGB(0x100, 1); \
} while (0)

// A-half mh of buf p -> a[4][2] (4 m-frags x 2 kk-halves), zero-conflict pattern
#define LD_A(p, mh) do { \
    const u16* _rA = &lsA[(p)*16384 + ((mh)*128 + aRB)*64]; \
    a[0][0] = *(const bf16x8*)(_rA + cb0);        a[0][1] = *(const bf16x8*)(_rA + cb1); \
    a[1][0] = *(const bf16x8*)(_rA + 1024 + cb0); a[1][1] = *(const bf16x8*)(_rA + 1024 + cb1); \
    a[2][0] = *(const bf16x8*)(_rA + 2048 + cb0); a[2][1] = *(const bf16x8*)(_rA + 2048 + cb1); \
    a[3][0] = *(const bf16x8*)(_rA + 3072 + cb0); a[3][1] = *(const bf16x8*)(_rA + 3072 + cb1); \
} while (0)

// B-half nh of buf p -> breg[2][2] (2 n-frags x 2 kk-halves)
#define LD_B(p, nh, breg) do { \
    const u16* _rB = &lsB[(p)*16384 + ((nh)*128 + bRB)*64]; \
    breg[0][0] = *(const bf16x8*)(_rB + cb0);        breg[0][1] = *(const bf16x8*)(_rB + cb1); \
    breg[1][0] = *(const bf16x8*)(_rB + 1024 + cb0); breg[1][1] = *(const bf16x8*)(_rB + 1024 + cb1); \
} while (0)

#define MFMA1(am, c, ar, br) acc[am][c] = __builtin_amdgcn_mfma_f32_16x16x32_bf16(ar, br, acc[am][c], 0, 0, 0)
#define MFMA_Q(mh, nh, breg) do { \
    MFMA1((mh)*4+0, (nh)*2+0, a[0][0], breg[0][0]); MFMA1((mh)*4+0, (nh)*2+0, a[0][1], breg[0][1]); \
    MFMA1((mh)*4+0, (nh)*2+1, a[0][0], breg[1][0]); MFMA1((mh)*4+0, (nh)*2+1, a[0][1], breg[1][1]); \
    MFMA1((mh)*4+1, (nh)*2+0, a[1][0], breg[0][0]); MFMA1((mh)*4+1, (nh)*2+0, a[1][1], breg[0][1]); \
    MFMA1((mh)*4+1, (nh)*2+1, a[1][0], breg[1][0]); MFMA1((mh)*4+1, (nh)*2+1, a[1][1], breg[1][1]); \
    MFMA1((mh)*4+2, (nh)*2+0, a[2][0], breg[0][0]); MFMA1((mh)*4+2, (nh)*2+0, a[2][1], breg[0][1]); \
    MFMA1((mh)*4+2, (nh)*2+1, a[2][0], breg[1][0]); MFMA1((mh)*4+2, (nh)*2+1, a[2][1], breg[1][1]); \
    MFMA1((mh)*4+3, (nh)*2+0, a[3][0], breg[0][0]); MFMA1((mh)*4+3, (nh)*2+0, a[3][1], breg[0][1]); \
    MFMA1((mh)*4+3, (nh)*2+1, a[3][0], breg[1][0]); MFMA1((mh)*4+3, (nh)*2+1, a[3][1], breg[1][1]); \
} while (0)

#define STG_A(p, j, kt) gload16(pA[j] + (kt)*64, &lsA[(p)*16384 + (j)*4096 + wOff])
#define STG_B(p, j, kt) gload16(pB[j] + (kt)*64, &lsB[(p)*16384 + (j)*4096 + wOff])

__global__ __launch_bounds__(512, 2)
void gemm8_kernel(const u16* __restrict__ Ab, const u16* __restrict__ Wb,
                  const float* __restrict__ bias, float* __restrict__ Out) {
    __shared__ u16 lsA[2 * 256 * 64];
    __shared__ u16 lsB[2 * 256 * 64];

    const int tid = threadIdx.x;
    const int w = tid >> 6, lane = tid & 63;
    const int wr = w >> 2, wc = w & 3;
    const int l15 = lane & 15, l7 = lane & 7, lq = lane >> 4;

    // T1: XCD-aware bijective swizzle (512 blocks % 8 == 0)
    int raw = blockIdx.x;
    int swz = (raw & 7) * 64 + (raw >> 3);
    const int bm = swz >> 4, bn = swz & 15;
    const int m0 = bm * 256, n0 = bn * 256;

    // read-side bases (verified zero-conflict pattern)
    const int aRB = wr * 64 + l15;
    const int bRB = wc * 32 + l15;
    const int cb0 = ((0 + lq) ^ l7) * 8;
    const int cb1 = ((4 + lq) ^ l7) * 8;

    // staging per-thread values
    const int relRow = tid >> 3;
    const int cbl = (tid & 7) ^ (relRow & 7);
    const int gBaseA[4] = {0, 128, 64, 192};
    const u16* pA[4];
    const u16* pB[4];
#pragma unroll
    for (int j = 0; j < 4; ++j) {
        pA[j] = Ab + (size_t)(m0 + gBaseA[j] + relRow) * K_DIM + cbl * 8;
        int rl = j * 64 + relRow;
        int n = ((rl >> 5) & 3) * 64 + (rl >> 7) * 32 + (rl & 31);
        pB[j] = Wb + (size_t)(n0 + n) * K_DIM + cbl * 8;
    }
    const int wOff = w * 512;

    float bv[4];
#pragma unroll
    for (int c = 0; c < 4; ++c) bv[c] = bias[n0 + wc * 64 + (c >> 1) * 32 + (c & 1) * 16 + l15];

    f32x4 acc[8][4];
#pragma unroll
    for (int am = 0; am < 8; ++am)
#pragma unroll
        for (int c = 0; c < 4; ++c) acc[am][c] = (f32x4){0.f, 0.f, 0.f, 0.f};
    bf16x8 a[4][2], b0a[2][2], b1a[2][2];

    // ---- prologue: buf0 <- kt0 (4 half-tiles), buf1 <- kt1 (A0,B0,A1) ----
    STG_A(0, 0, 0); STG_A(0, 1, 0); STG_A(0, 2, 0); STG_A(0, 3, 0);
    STG_B(0, 0, 0); STG_B(0, 1, 0); STG_B(0, 2, 0); STG_B(0, 3, 0);
    STG_A(1, 0, 1); STG_A(1, 1, 1);
    STG_B(1, 0, 1); STG_B(1, 1, 1);
    STG_A(1, 2, 1); STG_A(1, 3, 1);
    WAIT_VM6();                 // buf0 drained; 6 buf1 ops in flight
    FENCE(); BAR();
    LD_A(0, 0); LD_B(0, 0, b0a);   // reads for P1 (buf0 published)
    FENCE();

#pragma unroll 1
    for (int i = 0; i < NITER; ++i) {
        const int t1  = 2 * i + 1;
        const int kt2 = (2 * i + 2) & (NKT - 1);   // wraps harmlessly on last iter
        const int kt3 = (2 * i + 3) & (NKT - 1);

        // P1: Q(0,0) buf0 ∥ LD b1<-buf0.nh1 (SGB) | STG buf1.B(nh1) <- t1
        STG_B(1, 2, t1); STG_B(1, 3, t1);
        FENCE(); WAIT_LGKM0(); SCHEDB();
        PRIO1(); MFMA_Q(0, 0, b0a); PRIO0();
        LD_B(0, 1, b1a);
        SGB_MIX4();
        FENCE(); BAR();

        // P2: Q(0,1) buf0 ∥ LD a<-buf0.mh1 (SGB) | STG buf0.A(mh0) <- kt2
        STG_A(0, 0, kt2); STG_A(0, 1, kt2);
        FENCE(); WAIT_LGKM0(); SCHEDB();
        PRIO1(); MFMA_Q(0, 1, b1a); PRIO0();
        LD_A(0, 1);
        SGB_MIX8();
        FENCE(); BAR();

        // P3: Q(1,0) buf0 | STG buf0.B(nh0) | VM4: buf1(t1) landed | publish
        STG_B(0, 0, kt2); STG_B(0, 1, kt2);
        FENCE(); WAIT_LGKM0(); SCHEDB();
        PRIO1(); MFMA_Q(1, 0, b0a); PRIO0();
        WAIT_VM4();
        FENCE(); BAR(); FENCE();

        // P4: Q(1,1) buf0 ∥ LD b0 <- buf1.nh0 (SGB; published at P3) | STG buf0.A(mh1)
        //     post-BAR: a <- buf1.mh0
        STG_A(0, 2, kt2); STG_A(0, 3, kt2);
        FENCE();
        PRIO1(); MFMA_Q(1, 1, b1a); PRIO0();
        LD_B(1, 0, b0a);
        SGB_MIX4();
        FENCE(); BAR(); FENCE();
        LD_A(1, 0);

        // P5: Q(0,0) buf1 ∥ LD b1<-buf1.nh1 (SGB) | STG buf0.B(nh1) <- kt2
        STG_B(0, 2, kt2); STG_B(0, 3, kt2);
        FENCE(); WAIT_LGKM0(); SCHEDB();
        PRIO1(); MFMA_Q(0, 0, b0a); PRIO0();
        LD_B(1, 1, b1a);
        SGB_MIX4();
        FENCE(); BAR();

        // P6: Q(0,1) buf1 ∥ LD a<-buf1.mh1 (SGB) | STG buf1.A(mh0) <- kt3
        STG_A(1, 0, kt3); STG_A(1, 1, kt3);
        FENCE(); WAIT_LGKM0(); SCHEDB();
        PRIO1(); MFMA_Q(0, 1, b1a); PRIO0();
        LD_A(1, 1);
        SGB_MIX8();
        FENCE(); BAR();

        // P7: Q(1,0) buf1 | STG buf1.B(nh0) | VM4: buf0(kt2) landed | publish
        STG_B(1, 0, kt3); STG_B(1, 1, kt3);
        FENCE(); WAIT_LGKM0(); SCHEDB();
        PRIO1(); MFMA_Q(1, 0, b0a); PRIO0();
        WAIT_VM4();
        FENCE(); BAR(); FENCE();

        // P8: Q(1,1) buf1 ∥ LD b0 <- buf0.nh0 (SGB) | STG buf1.A(mh1)
        //     post-BAR: a <- buf0.mh0 (next iter P1)
        STG_A(1, 2, kt3); STG_A(1, 3, kt3);
        FENCE();
        PRIO1(); MFMA_Q(1, 1, b1a); PRIO0();
        LD_B(0, 0, b0a);
        SGB_MIX4();
        FENCE(); BAR(); FENCE();
        LD_A(0, 0);
    }

    // ---- epilogue: C/D layout col=lane&15, row=(lane>>4)*4+j ----
#pragma unroll
    for (int am = 0; am < 8; ++am) {
        const int gm = m0 + wr * 128 + (am >> 2) * 64 + (am & 3) * 16 + lq * 4;
#pragma unroll
        for (int c = 0; c < 4; ++c) {
            const int gn = n0 + wc * 64 + (c >> 1) * 32 + (c & 1) * 16 + l15;
            float* op = Out + (size_t)gm * N_DIM + gn;
#pragma unroll
            for (int j = 0; j < 4; ++j)
                op[(size_t)j * N_DIM] = acc[am][c][j] + bv[c];
        }
    }
}

// ---------------- Fallback: naive fused fp32 ----------------
__global__ void naive_kernel(const float* __restrict__ In, const int* __restrict__ codes,
                             const float* __restrict__ cbs, const float* __restrict__ scales,
                             const float* __restrict__ bias, float* __restrict__ Out) {
    int m = blockIdx.x >> 4;
    int n = ((blockIdx.x & 15) << 8) + threadIdx.x;
    const float* x = In + (size_t)m * K_DIM;
    const int* cr = codes + (size_t)n * 512 * 2;
    float acc = 0.f;
    for (int ig = 0; ig < 512; ++ig) {
        int c0 = cr[ig * 2], c1 = cr[ig * 2 + 1];
        const float* e0 = cbs + (size_t)c0 * 8;
        const float* e1 = cbs + 2048 + (size_t)c1 * 8;
        const float* xx = x + ig * 8;
#pragma unroll
        for (int j = 0; j < 8; ++j) acc += xx[j] * (e0[j] + e1[j]);
    }
    Out[(size_t)m * N_DIM + n] = acc * scales[n] + bias[n];
}

extern "C" void kernel_launch(void* const* d_in, const int* in_sizes, int n_in,
                              void* d_out, int out_size, void* d_ws, size_t ws_size,
                              hipStream_t stream) {
    const float* In     = (const float*)d_in[0];
    const int*   codes  = (const int*)d_in[1];
    const float* cbs    = (const float*)d_in[2];
    const float* scales = (const float*)d_in[3];
    const float* bias   = (const float*)d_in[4];
    float* Out = (float*)d_out;

    const size_t aBytes = (size_t)M_DIM * K_DIM * 2;
    const size_t wBytes = (size_t)N_DIM * K_DIM * 2;
    if (ws_size >= aBytes + wBytes) {
        u16* Ab = (u16*)d_ws;
        u16* Wb = (u16*)((char*)d_ws + aBytes);
        cvt_a_kernel<<<dim3((M_DIM * K_DIM) / (256 * 8)), dim3(256), 0, stream>>>(In, Ab);
        dequant_w_kernel<<<dim3((N_DIM * 512) / 256), dim3(256), 0, stream>>>(codes, cbs, scales, Wb);
        gemm8_kernel<<<dim3((M_DIM / 256) * (N_DIM / 256)), dim3(512), 0, stream>>>(Ab, Wb, bias, Out);
    } else {
        naive_kernel<<<dim3(M_DIM * (N_DIM / 256)), dim3(256), 0, stream>>>(In, codes, cbs, scales, bias, Out);
    }
}